// Round 10
// baseline (294.976 us; speedup 1.0000x reference)
//
#include <hip/hip_runtime.h>
#include <math.h>

#define THREADS 256
// fp32-vs-fp64 p error is <~3e-6 worst case; 1e-4 margin is ~30x safety.
#define P_MARGIN 1e-4f
#define FIXCAP 32

// Exact JAX threefry2x32 (20 rounds, key schedule every 4), key = (0, 42).
// Partitionable stream: bits[j] = o0 ^ o1 of threefry2x32(key, 0, j).
__device__ __forceinline__ void tf2x32(unsigned x0, unsigned x1,
                                       unsigned &o0, unsigned &o1) {
  const unsigned k0 = 0u;
  const unsigned k1 = 42u;
  const unsigned k2 = 0x1BD11BDAu ^ k0 ^ k1;
  x0 += k0; x1 += k1;
#define TF_R(r) { x0 += x1; x1 = (x1 << (r)) | (x1 >> (32 - (r))); x1 ^= x0; }
  TF_R(13) TF_R(15) TF_R(26) TF_R(6)
  x0 += k1; x1 += k2 + 1u;
  TF_R(17) TF_R(29) TF_R(16) TF_R(24)
  x0 += k2; x1 += k0 + 2u;
  TF_R(13) TF_R(15) TF_R(26) TF_R(6)
  x0 += k0; x1 += k1 + 3u;
  TF_R(17) TF_R(29) TF_R(16) TF_R(24)
  x0 += k1; x1 += k2 + 4u;
  TF_R(13) TF_R(15) TF_R(26) TF_R(6)
  x0 += k2; x1 += k0 + 5u;
#undef TF_R
  o0 = x0; o1 = x1;
}

// Single fused kernel:
//  - fp32 fast path, R8's scalar-FMA structure (uniform weight addresses ->
//    s_load through scalar cache; one fetch per wave; measured 106-117us at
//    VALUBusy 63%, VGPR 44). R9's packed-f32 variant REGRESSED (108->136us):
//    halving VALU issues exposed the SMEM-wait floor. So instead we attack
//    the stall with occupancy: launch_bounds(256,8) doubles waves/SIMD
//    (VGPR=44 fits 8 blocks/CU) so scalar-load latency hides behind other
//    waves' VALU issue.
//  - rows whose bernoulli comparison is within P_MARGIN of the threshold go
//    to a per-block LDS list; after a barrier the block re-runs them in fp64
//    (lane=neuron, R7-validated shape) and overwrites. ~0.4 rows/block.
__global__ __launch_bounds__(THREADS, 8)
void wtf_kernel(const float* __restrict__ events,
                const float* __restrict__ W1, const float* __restrict__ b1,
                const float* __restrict__ g1, const float* __restrict__ be1,
                const float* __restrict__ W2, const float* __restrict__ b2,
                const float* __restrict__ g2, const float* __restrict__ be2,
                const float* __restrict__ W3, const float* __restrict__ b3,
                const float* __restrict__ g3, const float* __restrict__ be3,
                const float* __restrict__ W4, const float* __restrict__ b4,
                const float* __restrict__ W5, const float* __restrict__ b5,
                float* __restrict__ out_chosen,
                float* __restrict__ out_logp,
                int B) {
  __shared__ unsigned s_cnt;
  __shared__ unsigned s_rows[FIXCAP];
  __shared__ double sA[64];
  __shared__ double sB[64];
  __shared__ double sF[8];

  const int t = threadIdx.x;
  if (t == 0) s_cnt = 0;
  __syncthreads();

  const int b = blockIdx.x * THREADS + t;
  const bool active = (b < B);
  const float rden = (float)(1.0 / sqrt(1.0 + 1e-5));

  if (active) {
    float x[32];
    const float4* ev4 = reinterpret_cast<const float4*>(events) + (size_t)b * 8;
#pragma unroll
    for (int q = 0; q < 8; ++q) {
      float4 v = ev4[q];
      x[4 * q + 0] = v.x; x[4 * q + 1] = v.y; x[4 * q + 2] = v.z; x[4 * q + 3] = v.w;
    }

    // layer 1: 32 -> 50, BN(eval) + ReLU
    float a1[50];
#pragma unroll
    for (int n = 0; n < 50; ++n) a1[n] = b1[n];
#pragma unroll
    for (int k = 0; k < 32; ++k) {
      const float xk = x[k];
#pragma unroll
      for (int n = 0; n < 50; ++n) a1[n] = fmaf(xk, W1[k * 50 + n], a1[n]);
    }
#pragma unroll
    for (int n = 0; n < 50; ++n) {
      float s = fmaf(a1[n], g1[n] * rden, be1[n]);
      a1[n] = fmaxf(s, 0.f);
    }

    // layer 2: 50 -> 30, BN(eval) + ReLU
    float a2[30];
#pragma unroll
    for (int n = 0; n < 30; ++n) a2[n] = b2[n];
#pragma unroll
    for (int k = 0; k < 50; ++k) {
      const float ak = a1[k];
#pragma unroll
      for (int n = 0; n < 30; ++n) a2[n] = fmaf(ak, W2[k * 30 + n], a2[n]);
    }
#pragma unroll
    for (int n = 0; n < 30; ++n) {
      float s = fmaf(a2[n], g2[n] * rden, be2[n]);
      a2[n] = fmaxf(s, 0.f);
    }

    // layer 3: 30 -> 20, BN(eval) + ReLU
    float a3[20];
#pragma unroll
    for (int n = 0; n < 20; ++n) a3[n] = b3[n];
#pragma unroll
    for (int k = 0; k < 30; ++k) {
      const float ak = a2[k];
#pragma unroll
      for (int n = 0; n < 20; ++n) a3[n] = fmaf(ak, W3[k * 20 + n], a3[n]);
    }
#pragma unroll
    for (int n = 0; n < 20; ++n) {
      float s = fmaf(a3[n], g3[n] * rden, be3[n]);
      a3[n] = fmaxf(s, 0.f);
    }

    // layer 4: 20 -> 15, ReLU (no BN)
    float a4[15];
#pragma unroll
    for (int n = 0; n < 15; ++n) a4[n] = b4[n];
#pragma unroll
    for (int k = 0; k < 20; ++k) {
      const float ak = a3[k];
#pragma unroll
      for (int n = 0; n < 15; ++n) a4[n] = fmaf(ak, W4[k * 15 + n], a4[n]);
    }
#pragma unroll
    for (int n = 0; n < 15; ++n) a4[n] = fmaxf(a4[n], 0.f);

    // layer 5: 15 -> 8, sigmoid
    float p[8];
#pragma unroll
    for (int n = 0; n < 8; ++n) p[n] = b5[n];
#pragma unroll
    for (int k = 0; k < 15; ++k) {
      const float ak = a4[k];
#pragma unroll
      for (int n = 0; n < 8; ++n) p[n] = fmaf(ak, W5[k * 8 + n], p[n]);
    }
#pragma unroll
    for (int n = 0; n < 8; ++n) p[n] = 1.f / (1.f + expf(-p[n]));

    // bernoulli(1-p) via partitionable threefry + margin flag
    bool need = false;
    float prod = 1.f;
    float ch[8];
#pragma unroll
    for (int w = 0; w < 8; ++w) {
      unsigned j = 8u * (unsigned)b + (unsigned)w, o0, o1;
      tf2x32(0u, j, o0, o1);
      unsigned bits = o0 ^ o1;
      float u = __uint_as_float(0x3F800000u | (bits >> 9)) - 1.f;
      float thr = 1.f - p[w];
      bool choice = u < thr;
      need = need || (fabsf(u - thr) < P_MARGIN);
      ch[w] = choice ? 0.f : 1.f;
      prod *= choice ? thr : p[w];
    }
    if (need) {
      unsigned i = atomicAdd(&s_cnt, 1u);
      if (i < FIXCAP) s_rows[i] = (unsigned)b;
    }

    float4* oc = reinterpret_cast<float4*>(out_chosen) + (size_t)b * 2;
    oc[0] = make_float4(ch[0], ch[1], ch[2], ch[3]);
    oc[1] = make_float4(ch[4], ch[5], ch[6], ch[7]);
    out_logp[b] = logf(prod);
  }

  // ---- block-cooperative fp64 repair of flagged rows (overwrites) ----
  __syncthreads();  // drains this block's fp32 stores before overwrite
  unsigned cnt = s_cnt;
  if (cnt > FIXCAP) cnt = FIXCAP;
  if (cnt == 0) return;

  const double denom = sqrt(1.0 + 1e-5);
  for (unsigned r = 0; r < cnt; ++r) {  // cnt is block-uniform
    const int rb = (int)s_rows[r];

    if (t < 32) sA[t] = (double)events[(size_t)rb * 32 + t];
    __syncthreads();

    double v = 0.0;
    if (t < 50) {
#pragma unroll
      for (int k = 0; k < 32; ++k) v = fma(sA[k], (double)W1[k * 50 + t], v);
      v += (double)b1[t];
      v = v * ((double)g1[t] / denom) + (double)be1[t];
      v = v > 0.0 ? v : 0.0;
    }
    __syncthreads();
    if (t < 50) sB[t] = v;
    __syncthreads();

    v = 0.0;
    if (t < 30) {
#pragma unroll
      for (int k = 0; k < 50; ++k) v = fma(sB[k], (double)W2[k * 30 + t], v);
      v += (double)b2[t];
      v = v * ((double)g2[t] / denom) + (double)be2[t];
      v = v > 0.0 ? v : 0.0;
    }
    __syncthreads();
    if (t < 30) sA[t] = v;
    __syncthreads();

    v = 0.0;
    if (t < 20) {
#pragma unroll
      for (int k = 0; k < 30; ++k) v = fma(sA[k], (double)W3[k * 20 + t], v);
      v += (double)b3[t];
      v = v * ((double)g3[t] / denom) + (double)be3[t];
      v = v > 0.0 ? v : 0.0;
    }
    __syncthreads();
    if (t < 20) sB[t] = v;
    __syncthreads();

    v = 0.0;
    if (t < 15) {
#pragma unroll
      for (int k = 0; k < 20; ++k) v = fma(sB[k], (double)W4[k * 15 + t], v);
      v += (double)b4[t];
      v = v > 0.0 ? v : 0.0;
    }
    __syncthreads();
    if (t < 15) sA[t] = v;
    __syncthreads();

    if (t < 8) {
      v = 0.0;
#pragma unroll
      for (int k = 0; k < 15; ++k) v = fma(sA[k], (double)W5[k * 8 + t], v);
      v += (double)b5[t];
      double p = 1.0 / (1.0 + exp(-v));
      unsigned j = 8u * (unsigned)rb + (unsigned)t, o0, o1;
      tf2x32(0u, j, o0, o1);
      unsigned bits = o0 ^ o1;
      float u = __uint_as_float(0x3F800000u | (bits >> 9)) - 1.f;
      double thr = 1.0 - p;
      bool choice = ((double)u < thr);
      out_chosen[(size_t)rb * 8 + t] = choice ? 0.f : 1.f;
      sF[t] = choice ? thr : p;
    }
    __syncthreads();
    if (t == 0) {
      double prod = 1.0;
      for (int w = 0; w < 8; ++w) prod *= sF[w];
      out_logp[rb] = (float)log(prod);
    }
    __syncthreads();
  }
}

extern "C" void kernel_launch(void* const* d_in, const int* in_sizes, int n_in,
                              void* d_out, int out_size, void* d_ws, size_t ws_size,
                              hipStream_t stream) {
  const float* events = (const float*)d_in[0];
  const float* W1  = (const float*)d_in[1];
  const float* b1  = (const float*)d_in[2];
  const float* g1  = (const float*)d_in[3];
  const float* be1 = (const float*)d_in[4];
  const float* W2  = (const float*)d_in[5];
  const float* b2  = (const float*)d_in[6];
  const float* g2  = (const float*)d_in[7];
  const float* be2 = (const float*)d_in[8];
  const float* W3  = (const float*)d_in[9];
  const float* b3  = (const float*)d_in[10];
  const float* g3  = (const float*)d_in[11];
  const float* be3 = (const float*)d_in[12];
  const float* W4  = (const float*)d_in[13];
  const float* b4  = (const float*)d_in[14];
  const float* W5  = (const float*)d_in[15];
  const float* b5  = (const float*)d_in[16];

  const int B = in_sizes[0] / 32;  // 524288
  float* out = (float*)d_out;
  float* out_chosen = out;                   // (B, 8)
  float* out_logp   = out + (size_t)B * 8;   // (B,)

  const int blocks = (B + THREADS - 1) / THREADS;
  hipLaunchKernelGGL(wtf_kernel, dim3(blocks), dim3(THREADS), 0, stream,
                     events, W1, b1, g1, be1, W2, b2, g2, be2,
                     W3, b3, g3, be3, W4, b4, W5, b5,
                     out_chosen, out_logp, B);
}

// Round 11
// 247.820 us; speedup vs baseline: 1.1903x; 1.1903x over previous
//
#include <hip/hip_runtime.h>
#include <math.h>

#define THREADS 256
// fp32-vs-fp64 p error is <~3e-6 worst case; 1e-4 margin is ~30x safety.
#define P_MARGIN 1e-4f
#define FIXCAP 32

// Exact JAX threefry2x32 (20 rounds, key schedule every 4), key = (0, 42).
// Partitionable stream: bits[j] = o0 ^ o1 of threefry2x32(key, 0, j).
__device__ __forceinline__ void tf2x32(unsigned x0, unsigned x1,
                                       unsigned &o0, unsigned &o1) {
  const unsigned k0 = 0u;
  const unsigned k1 = 42u;
  const unsigned k2 = 0x1BD11BDAu ^ k0 ^ k1;
  x0 += k0; x1 += k1;
#define TF_R(r) { x0 += x1; x1 = (x1 << (r)) | (x1 >> (32 - (r))); x1 ^= x0; }
  TF_R(13) TF_R(15) TF_R(26) TF_R(6)
  x0 += k1; x1 += k2 + 1u;
  TF_R(17) TF_R(29) TF_R(16) TF_R(24)
  x0 += k2; x1 += k0 + 2u;
  TF_R(13) TF_R(15) TF_R(26) TF_R(6)
  x0 += k0; x1 += k1 + 3u;
  TF_R(17) TF_R(29) TF_R(16) TF_R(24)
  x0 += k1; x1 += k2 + 4u;
  TF_R(13) TF_R(15) TF_R(26) TF_R(6)
  x0 += k2; x1 += k0 + 5u;
#undef TF_R
  o0 = x0; o1 = x1;
}

// Single fused kernel = R8's fast path (verbatim body; measured 106-117us,
// VGPR=44, VALUBusy 63%) + R9's in-block fp64 repair tail (kills the memset
// + second dispatch, ~15-20us of launch/sync overhead).
// Allocator lessons (R6/R7/R10): any config whose live set exceeds ~64
// floats is spill-roulette on this backend — (256,4) with this exact body
// is the only repeatedly-measured-good point. Do not perturb.
__global__ __launch_bounds__(THREADS, 4)
void wtf_kernel(const float* __restrict__ events,
                const float* __restrict__ W1, const float* __restrict__ b1,
                const float* __restrict__ g1, const float* __restrict__ be1,
                const float* __restrict__ W2, const float* __restrict__ b2,
                const float* __restrict__ g2, const float* __restrict__ be2,
                const float* __restrict__ W3, const float* __restrict__ b3,
                const float* __restrict__ g3, const float* __restrict__ be3,
                const float* __restrict__ W4, const float* __restrict__ b4,
                const float* __restrict__ W5, const float* __restrict__ b5,
                float* __restrict__ out_chosen,
                float* __restrict__ out_logp,
                int B) {
  __shared__ unsigned s_cnt;
  __shared__ unsigned s_rows[FIXCAP];
  __shared__ double sA[64];
  __shared__ double sB[64];
  __shared__ double sF[8];

  const int t = threadIdx.x;
  if (t == 0) s_cnt = 0;
  __syncthreads();

  const int b = blockIdx.x * THREADS + t;
  const bool active = (b < B);
  const float rden = (float)(1.0 / sqrt(1.0 + 1e-5));

  if (active) {
    float x[32];
    const float4* ev4 = reinterpret_cast<const float4*>(events) + (size_t)b * 8;
#pragma unroll
    for (int q = 0; q < 8; ++q) {
      float4 v = ev4[q];
      x[4 * q + 0] = v.x; x[4 * q + 1] = v.y; x[4 * q + 2] = v.z; x[4 * q + 3] = v.w;
    }

    // layer 1: 32 -> 50, BN(eval) + ReLU
    float a1[50];
#pragma unroll
    for (int n = 0; n < 50; ++n) a1[n] = b1[n];
#pragma unroll
    for (int k = 0; k < 32; ++k) {
      const float xk = x[k];
#pragma unroll
      for (int n = 0; n < 50; ++n) a1[n] = fmaf(xk, W1[k * 50 + n], a1[n]);
    }
#pragma unroll
    for (int n = 0; n < 50; ++n) {
      float s = fmaf(a1[n], g1[n] * rden, be1[n]);
      a1[n] = fmaxf(s, 0.f);
    }

    // layer 2: 50 -> 30, BN(eval) + ReLU
    float a2[30];
#pragma unroll
    for (int n = 0; n < 30; ++n) a2[n] = b2[n];
#pragma unroll
    for (int k = 0; k < 50; ++k) {
      const float ak = a1[k];
#pragma unroll
      for (int n = 0; n < 30; ++n) a2[n] = fmaf(ak, W2[k * 30 + n], a2[n]);
    }
#pragma unroll
    for (int n = 0; n < 30; ++n) {
      float s = fmaf(a2[n], g2[n] * rden, be2[n]);
      a2[n] = fmaxf(s, 0.f);
    }

    // layer 3: 30 -> 20, BN(eval) + ReLU
    float a3[20];
#pragma unroll
    for (int n = 0; n < 20; ++n) a3[n] = b3[n];
#pragma unroll
    for (int k = 0; k < 30; ++k) {
      const float ak = a2[k];
#pragma unroll
      for (int n = 0; n < 20; ++n) a3[n] = fmaf(ak, W3[k * 20 + n], a3[n]);
    }
#pragma unroll
    for (int n = 0; n < 20; ++n) {
      float s = fmaf(a3[n], g3[n] * rden, be3[n]);
      a3[n] = fmaxf(s, 0.f);
    }

    // layer 4: 20 -> 15, ReLU (no BN)
    float a4[15];
#pragma unroll
    for (int n = 0; n < 15; ++n) a4[n] = b4[n];
#pragma unroll
    for (int k = 0; k < 20; ++k) {
      const float ak = a3[k];
#pragma unroll
      for (int n = 0; n < 15; ++n) a4[n] = fmaf(ak, W4[k * 15 + n], a4[n]);
    }
#pragma unroll
    for (int n = 0; n < 15; ++n) a4[n] = fmaxf(a4[n], 0.f);

    // layer 5: 15 -> 8, sigmoid
    float p[8];
#pragma unroll
    for (int n = 0; n < 8; ++n) p[n] = b5[n];
#pragma unroll
    for (int k = 0; k < 15; ++k) {
      const float ak = a4[k];
#pragma unroll
      for (int n = 0; n < 8; ++n) p[n] = fmaf(ak, W5[k * 8 + n], p[n]);
    }
#pragma unroll
    for (int n = 0; n < 8; ++n) p[n] = 1.f / (1.f + expf(-p[n]));

    // bernoulli(1-p) via partitionable threefry + margin flag
    bool need = false;
    float prod = 1.f;
    float ch[8];
#pragma unroll
    for (int w = 0; w < 8; ++w) {
      unsigned j = 8u * (unsigned)b + (unsigned)w, o0, o1;
      tf2x32(0u, j, o0, o1);
      unsigned bits = o0 ^ o1;
      float u = __uint_as_float(0x3F800000u | (bits >> 9)) - 1.f;
      float thr = 1.f - p[w];
      bool choice = u < thr;
      need = need || (fabsf(u - thr) < P_MARGIN);
      ch[w] = choice ? 0.f : 1.f;
      prod *= choice ? thr : p[w];
    }
    if (need) {
      unsigned i = atomicAdd(&s_cnt, 1u);
      if (i < FIXCAP) s_rows[i] = (unsigned)b;
    }

    float4* oc = reinterpret_cast<float4*>(out_chosen) + (size_t)b * 2;
    oc[0] = make_float4(ch[0], ch[1], ch[2], ch[3]);
    oc[1] = make_float4(ch[4], ch[5], ch[6], ch[7]);
    out_logp[b] = logf(prod);
  }

  // ---- block-cooperative fp64 repair of flagged rows (overwrites) ----
  __syncthreads();  // drains this block's fp32 stores before overwrite
  unsigned cnt = s_cnt;
  if (cnt > FIXCAP) cnt = FIXCAP;
  if (cnt == 0) return;

  const double denom = sqrt(1.0 + 1e-5);
  for (unsigned r = 0; r < cnt; ++r) {  // cnt is block-uniform
    const int rb = (int)s_rows[r];

    if (t < 32) sA[t] = (double)events[(size_t)rb * 32 + t];
    __syncthreads();

    double v = 0.0;
    if (t < 50) {
#pragma unroll
      for (int k = 0; k < 32; ++k) v = fma(sA[k], (double)W1[k * 50 + t], v);
      v += (double)b1[t];
      v = v * ((double)g1[t] / denom) + (double)be1[t];
      v = v > 0.0 ? v : 0.0;
    }
    __syncthreads();
    if (t < 50) sB[t] = v;
    __syncthreads();

    v = 0.0;
    if (t < 30) {
#pragma unroll
      for (int k = 0; k < 50; ++k) v = fma(sB[k], (double)W2[k * 30 + t], v);
      v += (double)b2[t];
      v = v * ((double)g2[t] / denom) + (double)be2[t];
      v = v > 0.0 ? v : 0.0;
    }
    __syncthreads();
    if (t < 30) sA[t] = v;
    __syncthreads();

    v = 0.0;
    if (t < 20) {
#pragma unroll
      for (int k = 0; k < 30; ++k) v = fma(sA[k], (double)W3[k * 20 + t], v);
      v += (double)b3[t];
      v = v * ((double)g3[t] / denom) + (double)be3[t];
      v = v > 0.0 ? v : 0.0;
    }
    __syncthreads();
    if (t < 20) sB[t] = v;
    __syncthreads();

    v = 0.0;
    if (t < 15) {
#pragma unroll
      for (int k = 0; k < 20; ++k) v = fma(sB[k], (double)W4[k * 15 + t], v);
      v += (double)b4[t];
      v = v > 0.0 ? v : 0.0;
    }
    __syncthreads();
    if (t < 15) sA[t] = v;
    __syncthreads();

    if (t < 8) {
      v = 0.0;
#pragma unroll
      for (int k = 0; k < 15; ++k) v = fma(sA[k], (double)W5[k * 8 + t], v);
      v += (double)b5[t];
      double p = 1.0 / (1.0 + exp(-v));
      unsigned j = 8u * (unsigned)rb + (unsigned)t, o0, o1;
      tf2x32(0u, j, o0, o1);
      unsigned bits = o0 ^ o1;
      float u = __uint_as_float(0x3F800000u | (bits >> 9)) - 1.f;
      double thr = 1.0 - p;
      bool choice = ((double)u < thr);
      out_chosen[(size_t)rb * 8 + t] = choice ? 0.f : 1.f;
      sF[t] = choice ? thr : p;
    }
    __syncthreads();
    if (t == 0) {
      double prod = 1.0;
      for (int w = 0; w < 8; ++w) prod *= sF[w];
      out_logp[rb] = (float)log(prod);
    }
    __syncthreads();
  }
}

extern "C" void kernel_launch(void* const* d_in, const int* in_sizes, int n_in,
                              void* d_out, int out_size, void* d_ws, size_t ws_size,
                              hipStream_t stream) {
  const float* events = (const float*)d_in[0];
  const float* W1  = (const float*)d_in[1];
  const float* b1  = (const float*)d_in[2];
  const float* g1  = (const float*)d_in[3];
  const float* be1 = (const float*)d_in[4];
  const float* W2  = (const float*)d_in[5];
  const float* b2  = (const float*)d_in[6];
  const float* g2  = (const float*)d_in[7];
  const float* be2 = (const float*)d_in[8];
  const float* W3  = (const float*)d_in[9];
  const float* b3  = (const float*)d_in[10];
  const float* g3  = (const float*)d_in[11];
  const float* be3 = (const float*)d_in[12];
  const float* W4  = (const float*)d_in[13];
  const float* b4  = (const float*)d_in[14];
  const float* W5  = (const float*)d_in[15];
  const float* b5  = (const float*)d_in[16];

  const int B = in_sizes[0] / 32;  // 524288
  float* out = (float*)d_out;
  float* out_chosen = out;                   // (B, 8)
  float* out_logp   = out + (size_t)B * 8;   // (B,)

  const int blocks = (B + THREADS - 1) / THREADS;
  hipLaunchKernelGGL(wtf_kernel, dim3(blocks), dim3(THREADS), 0, stream,
                     events, W1, b1, g1, be1, W2, b2, g2, be2,
                     W3, b3, g3, be3, W4, b4, W5, b5,
                     out_chosen, out_logp, B);
}

// Round 12
// 236.520 us; speedup vs baseline: 1.2472x; 1.0478x over previous
//
#include <hip/hip_runtime.h>
#include <math.h>

#define THREADS 256
// fp32-vs-fp64 p error is <~3e-6 worst case; 1e-4 margin is ~30x safety.
#define P_MARGIN 1e-4f

typedef float v2f __attribute__((ext_vector_type(2)));

// Exact JAX threefry2x32 (20 rounds, key schedule every 4), key = (0, 42).
// Partitionable stream: bits[j] = o0 ^ o1 of threefry2x32(key, 0, j).
__device__ __forceinline__ void tf2x32(unsigned x0, unsigned x1,
                                       unsigned &o0, unsigned &o1) {
  const unsigned k0 = 0u;
  const unsigned k1 = 42u;
  const unsigned k2 = 0x1BD11BDAu ^ k0 ^ k1;
  x0 += k0; x1 += k1;
#define TF_R(r) { x0 += x1; x1 = (x1 << (r)) | (x1 >> (32 - (r))); x1 ^= x0; }
  TF_R(13) TF_R(15) TF_R(26) TF_R(6)
  x0 += k1; x1 += k2 + 1u;
  TF_R(17) TF_R(29) TF_R(16) TF_R(24)
  x0 += k2; x1 += k0 + 2u;
  TF_R(13) TF_R(15) TF_R(26) TF_R(6)
  x0 += k0; x1 += k1 + 3u;
  TF_R(17) TF_R(29) TF_R(16) TF_R(24)
  x0 += k1; x1 += k2 + 4u;
  TF_R(13) TF_R(15) TF_R(26) TF_R(6)
  x0 += k2; x1 += k0 + 5u;
#undef TF_R
  o0 = x0; o1 = x1;
}

// ---------------- Pass 1: fp32 fast path, packed f32x2, standalone -------
// Two-kernel structure: R11 measured that fusing the fp64 repair tail into
// this kernel costs +38us of stall (VGPR 44->64, codegen contamination) to
// save ~20us of dispatch overhead - net loss. Packed v2f measured -10us in
// the fused context (R9 136 vs R11 146); applied here standalone.
// Weights via uniform addresses -> s_load scalar cache, one fetch per wave.
__global__ __launch_bounds__(THREADS, 4)
void wtf_fast_kernel(const float* __restrict__ events,
                     const float* __restrict__ W1, const float* __restrict__ b1,
                     const float* __restrict__ g1, const float* __restrict__ be1,
                     const float* __restrict__ W2, const float* __restrict__ b2,
                     const float* __restrict__ g2, const float* __restrict__ be2,
                     const float* __restrict__ W3, const float* __restrict__ b3,
                     const float* __restrict__ g3, const float* __restrict__ be3,
                     const float* __restrict__ W4, const float* __restrict__ b4,
                     const float* __restrict__ W5, const float* __restrict__ b5,
                     float* __restrict__ out_chosen,
                     float* __restrict__ out_logp,
                     unsigned* __restrict__ fixlist,  // [0]=count, rows at [1+i]
                     unsigned fixcap,
                     int B) {
  const int b = blockIdx.x * THREADS + threadIdx.x;
  if (b >= B) return;

  const float rden = (float)(1.0 / sqrt(1.0 + 1e-5));

  float x[32];
  const float4* ev4 = reinterpret_cast<const float4*>(events) + (size_t)b * 8;
#pragma unroll
  for (int q = 0; q < 8; ++q) {
    float4 v = ev4[q];
    x[4 * q + 0] = v.x; x[4 * q + 1] = v.y; x[4 * q + 2] = v.z; x[4 * q + 3] = v.w;
  }

  // ---- layer 1: 32 -> 50, BN + ReLU (packed f32x2 accumulators) ----
  v2f A[25];
#pragma unroll
  for (int j = 0; j < 25; ++j) A[j] = v2f{b1[2 * j], b1[2 * j + 1]};
#pragma unroll
  for (int k = 0; k < 32; ++k) {
    const v2f xk2 = {x[k], x[k]};
#pragma unroll
    for (int j = 0; j < 25; ++j) {
      v2f w = {W1[k * 50 + 2 * j], W1[k * 50 + 2 * j + 1]};
      A[j] = __builtin_elementwise_fma(xk2, w, A[j]);
    }
  }
  float a1[50];
#pragma unroll
  for (int j = 0; j < 25; ++j) {
    a1[2 * j + 0] = fmaxf(fmaf(A[j].x, g1[2 * j + 0] * rden, be1[2 * j + 0]), 0.f);
    a1[2 * j + 1] = fmaxf(fmaf(A[j].y, g1[2 * j + 1] * rden, be1[2 * j + 1]), 0.f);
  }

  // ---- layer 2: 50 -> 30, BN + ReLU ----
  v2f C[15];
#pragma unroll
  for (int j = 0; j < 15; ++j) C[j] = v2f{b2[2 * j], b2[2 * j + 1]};
#pragma unroll
  for (int k = 0; k < 50; ++k) {
    const v2f hk2 = {a1[k], a1[k]};
#pragma unroll
    for (int j = 0; j < 15; ++j) {
      v2f w = {W2[k * 30 + 2 * j], W2[k * 30 + 2 * j + 1]};
      C[j] = __builtin_elementwise_fma(hk2, w, C[j]);
    }
  }
  float a2[30];
#pragma unroll
  for (int j = 0; j < 15; ++j) {
    a2[2 * j + 0] = fmaxf(fmaf(C[j].x, g2[2 * j + 0] * rden, be2[2 * j + 0]), 0.f);
    a2[2 * j + 1] = fmaxf(fmaf(C[j].y, g2[2 * j + 1] * rden, be2[2 * j + 1]), 0.f);
  }

  // ---- layer 3: 30 -> 20, BN + ReLU ----
  v2f D[10];
#pragma unroll
  for (int j = 0; j < 10; ++j) D[j] = v2f{b3[2 * j], b3[2 * j + 1]};
#pragma unroll
  for (int k = 0; k < 30; ++k) {
    const v2f hk2 = {a2[k], a2[k]};
#pragma unroll
    for (int j = 0; j < 10; ++j) {
      v2f w = {W3[k * 20 + 2 * j], W3[k * 20 + 2 * j + 1]};
      D[j] = __builtin_elementwise_fma(hk2, w, D[j]);
    }
  }
  float a3[20];
#pragma unroll
  for (int j = 0; j < 10; ++j) {
    a3[2 * j + 0] = fmaxf(fmaf(D[j].x, g3[2 * j + 0] * rden, be3[2 * j + 0]), 0.f);
    a3[2 * j + 1] = fmaxf(fmaf(D[j].y, g3[2 * j + 1] * rden, be3[2 * j + 1]), 0.f);
  }

  // ---- layer 4: 20 -> 15, ReLU (no BN); 7 pairs + 1 scalar tail ----
  v2f E[7];
  float e14 = b4[14];
#pragma unroll
  for (int j = 0; j < 7; ++j) E[j] = v2f{b4[2 * j], b4[2 * j + 1]};
#pragma unroll
  for (int k = 0; k < 20; ++k) {
    const float hk = a3[k];
    const v2f hk2 = {hk, hk};
#pragma unroll
    for (int j = 0; j < 7; ++j) {
      v2f w = {W4[k * 15 + 2 * j], W4[k * 15 + 2 * j + 1]};
      E[j] = __builtin_elementwise_fma(hk2, w, E[j]);
    }
    e14 = fmaf(hk, W4[k * 15 + 14], e14);
  }
  float a4[15];
#pragma unroll
  for (int j = 0; j < 7; ++j) {
    a4[2 * j + 0] = fmaxf(E[j].x, 0.f);
    a4[2 * j + 1] = fmaxf(E[j].y, 0.f);
  }
  a4[14] = fmaxf(e14, 0.f);

  // ---- layer 5: 15 -> 8, sigmoid ----
  v2f P[4];
#pragma unroll
  for (int j = 0; j < 4; ++j) P[j] = v2f{b5[2 * j], b5[2 * j + 1]};
#pragma unroll
  for (int k = 0; k < 15; ++k) {
    const v2f hk2 = {a4[k], a4[k]};
#pragma unroll
    for (int j = 0; j < 4; ++j) {
      v2f w = {W5[k * 8 + 2 * j], W5[k * 8 + 2 * j + 1]};
      P[j] = __builtin_elementwise_fma(hk2, w, P[j]);
    }
  }
  float p[8];
#pragma unroll
  for (int j = 0; j < 4; ++j) {
    p[2 * j + 0] = 1.f / (1.f + expf(-P[j].x));
    p[2 * j + 1] = 1.f / (1.f + expf(-P[j].y));
  }

  // ---- bernoulli(1-p) via partitionable threefry + margin flag ----
  bool need = false;
  float prod = 1.f;
  float ch[8];
#pragma unroll
  for (int w = 0; w < 8; ++w) {
    unsigned j = 8u * (unsigned)b + (unsigned)w, o0, o1;
    tf2x32(0u, j, o0, o1);
    unsigned bits = o0 ^ o1;
    float u = __uint_as_float(0x3F800000u | (bits >> 9)) - 1.f;
    float thr = 1.f - p[w];
    bool choice = u < thr;
    need = need || (fabsf(u - thr) < P_MARGIN);
    ch[w] = choice ? 0.f : 1.f;
    prod *= choice ? thr : p[w];
  }
  if (need) {
    unsigned i = atomicAdd(&fixlist[0], 1u);
    if (i < fixcap) fixlist[1 + i] = (unsigned)b;
  }

  float4* oc = reinterpret_cast<float4*>(out_chosen) + (size_t)b * 2;
  oc[0] = make_float4(ch[0], ch[1], ch[2], ch[3]);
  oc[1] = make_float4(ch[4], ch[5], ch[6], ch[7]);
  out_logp[b] = logf(prod);
}

// ---------------- Pass 2: wave-cooperative fp64 repair -------------------
// One 64-lane wave per flagged row; lane n computes output neuron n. ~10
// regs/lane hot state, no spills. Validated shape (R7/R8/R9/R11).
__global__ __launch_bounds__(64, 4)
void wtf_fix_kernel(const float* __restrict__ events,
                    const float* __restrict__ W1, const float* __restrict__ b1,
                    const float* __restrict__ g1, const float* __restrict__ be1,
                    const float* __restrict__ W2, const float* __restrict__ b2,
                    const float* __restrict__ g2, const float* __restrict__ be2,
                    const float* __restrict__ W3, const float* __restrict__ b3,
                    const float* __restrict__ g3, const float* __restrict__ be3,
                    const float* __restrict__ W4, const float* __restrict__ b4,
                    const float* __restrict__ W5, const float* __restrict__ b5,
                    float* __restrict__ out_chosen,
                    float* __restrict__ out_logp,
                    const unsigned* __restrict__ fixlist,
                    unsigned fixcap,
                    int B) {
  const unsigned raw = fixlist[0];
  const unsigned cnt = raw < fixcap ? raw : fixcap;
  if (blockIdx.x >= cnt) return;

  __shared__ double sA[64];
  __shared__ double sB[64];
  __shared__ double sF[8];

  const int t = threadIdx.x;
  const double denom = sqrt(1.0 + 1e-5);

  for (unsigned idx = blockIdx.x; idx < cnt; idx += gridDim.x) {
    const int b = (int)fixlist[1 + idx];

    if (t < 32) sA[t] = (double)events[(size_t)b * 32 + t];
    __syncthreads();

    double v = 0.0;
    if (t < 50) {
#pragma unroll
      for (int k = 0; k < 32; ++k) v = fma(sA[k], (double)W1[k * 50 + t], v);
      v += (double)b1[t];
      v = v * ((double)g1[t] / denom) + (double)be1[t];
      v = v > 0.0 ? v : 0.0;
    }
    __syncthreads();
    if (t < 50) sB[t] = v;
    __syncthreads();

    v = 0.0;
    if (t < 30) {
#pragma unroll
      for (int k = 0; k < 50; ++k) v = fma(sB[k], (double)W2[k * 30 + t], v);
      v += (double)b2[t];
      v = v * ((double)g2[t] / denom) + (double)be2[t];
      v = v > 0.0 ? v : 0.0;
    }
    __syncthreads();
    if (t < 30) sA[t] = v;
    __syncthreads();

    v = 0.0;
    if (t < 20) {
#pragma unroll
      for (int k = 0; k < 30; ++k) v = fma(sA[k], (double)W3[k * 20 + t], v);
      v += (double)b3[t];
      v = v * ((double)g3[t] / denom) + (double)be3[t];
      v = v > 0.0 ? v : 0.0;
    }
    __syncthreads();
    if (t < 20) sB[t] = v;
    __syncthreads();

    v = 0.0;
    if (t < 15) {
#pragma unroll
      for (int k = 0; k < 20; ++k) v = fma(sB[k], (double)W4[k * 15 + t], v);
      v += (double)b4[t];
      v = v > 0.0 ? v : 0.0;
    }
    __syncthreads();
    if (t < 15) sA[t] = v;
    __syncthreads();

    if (t < 8) {
      v = 0.0;
#pragma unroll
      for (int k = 0; k < 15; ++k) v = fma(sA[k], (double)W5[k * 8 + t], v);
      v += (double)b5[t];
      double p = 1.0 / (1.0 + exp(-v));
      unsigned j = 8u * (unsigned)b + (unsigned)t, o0, o1;
      tf2x32(0u, j, o0, o1);
      unsigned bits = o0 ^ o1;
      float u = __uint_as_float(0x3F800000u | (bits >> 9)) - 1.f;
      double thr = 1.0 - p;
      bool choice = ((double)u < thr);
      out_chosen[(size_t)b * 8 + t] = choice ? 0.f : 1.f;
      sF[t] = choice ? thr : p;
    }
    __syncthreads();
    if (t == 0) {
      double prod = 1.0;
      for (int w = 0; w < 8; ++w) prod *= sF[w];
      out_logp[b] = (float)log(prod);
    }
    __syncthreads();
  }
}

extern "C" void kernel_launch(void* const* d_in, const int* in_sizes, int n_in,
                              void* d_out, int out_size, void* d_ws, size_t ws_size,
                              hipStream_t stream) {
  const float* events = (const float*)d_in[0];
  const float* W1  = (const float*)d_in[1];
  const float* b1  = (const float*)d_in[2];
  const float* g1  = (const float*)d_in[3];
  const float* be1 = (const float*)d_in[4];
  const float* W2  = (const float*)d_in[5];
  const float* b2  = (const float*)d_in[6];
  const float* g2  = (const float*)d_in[7];
  const float* be2 = (const float*)d_in[8];
  const float* W3  = (const float*)d_in[9];
  const float* b3  = (const float*)d_in[10];
  const float* g3  = (const float*)d_in[11];
  const float* be3 = (const float*)d_in[12];
  const float* W4  = (const float*)d_in[13];
  const float* b4  = (const float*)d_in[14];
  const float* W5  = (const float*)d_in[15];
  const float* b5  = (const float*)d_in[16];

  const int B = in_sizes[0] / 32;  // 524288
  float* out = (float*)d_out;
  float* out_chosen = out;                   // (B, 8)
  float* out_logp   = out + (size_t)B * 8;   // (B,)
  unsigned* fixlist = (unsigned*)d_ws;       // [0]=count, rows at [1+i]
  unsigned fixcap = (unsigned)(ws_size / sizeof(unsigned) - 1);
  if (fixcap > (unsigned)B) fixcap = (unsigned)B;

  hipMemsetAsync(d_ws, 0, sizeof(unsigned), stream);  // zero the counter

  const int blocks = (B + THREADS - 1) / THREADS;
  hipLaunchKernelGGL(wtf_fast_kernel, dim3(blocks), dim3(THREADS), 0, stream,
                     events, W1, b1, g1, be1, W2, b2, g2, be2,
                     W3, b3, g3, be3, W4, b4, W5, b5,
                     out_chosen, out_logp, fixlist, fixcap, B);
  hipLaunchKernelGGL(wtf_fix_kernel, dim3(512), dim3(64), 0, stream,
                     events, W1, b1, g1, be1, W2, b2, g2, be2,
                     W3, b3, g3, be3, W4, b4, W5, b5,
                     out_chosen, out_logp, fixlist, fixcap, B);
}